// Round 17
// baseline (151.542 us; speedup 1.0000x reference)
//
#include <hip/hip_runtime.h>
#include <hip/hip_bf16.h>

#define NB 8
#define BIN 512
#define BOUT 512
#define BATCH 8192
#define DIM 4096   // NB*BIN

typedef __attribute__((ext_vector_type(8))) short bf16x8;
typedef __attribute__((ext_vector_type(4))) float f32x4;

#define SWZ8(r) (((r) & 7) << 4)

__device__ __forceinline__ unsigned short f2bf(float f) {
    return __builtin_bit_cast(unsigned short, __float2bfloat16(f));
}

__device__ __forceinline__ unsigned long long pack4(f32x4 f) {
    return (unsigned long long)f2bf(f.x)
         | ((unsigned long long)f2bf(f.y) << 16)
         | ((unsigned long long)f2bf(f.z) << 32)
         | ((unsigned long long)f2bf(f.w) << 48);
}

// ---------------- weight pack (R11 layout) ----------------
// (nb, wid 0..7, kidx 0..15, nf 0..3, lane 0..63) x 8 ushorts, linear.
// Fragment: lane -> row = wid*64 + nf*16 + (lane&15), col = kidx*32 + (lane>>4)*8.
// Per (nb,wid): 32768 ush; per kidx: 2048 ush (4 frags).
__global__ void pack_w(const float* __restrict__ W, unsigned short* __restrict__ pk) {
    int gid = blockIdx.x * 256 + threadIdx.x;        // 262144 total
    int lane = gid & 63;
    int nf   = (gid >> 6) & 3;
    int kidx = (gid >> 8) & 15;
    int wid  = (gid >> 12) & 7;
    int nb   = gid >> 15;
    int row  = wid * 64 + nf * 16 + (lane & 15);
    int col  = kidx * 32 + (lane >> 4) * 8;
    const float* s = W + ((size_t)nb * BOUT + row) * BIN + col;
    f32x4 a = *(const f32x4*)s;
    f32x4 b = *(const f32x4*)(s + 4);
    unsigned long long* d = (unsigned long long*)(pk + (size_t)gid * 8);
    d[0] = pack4(a);
    d[1] = pack4(b);
}

// ---------------- fused 2-layer block-diag MLP ----------------
// R11 base (best: 97.9 us) + two changes:
// 1. W prefetch deepened to kidx-PAIRS (q0/q1 = 8 frags each): issue-to-use
//    lead ~2 halfsteps (~1000 cy) instead of ~350. Regs ~165 -> 3 waves/SIMD
//    (launch_bounds(512,3)); still 2 wgs/CU (LDS 68 KB).
// 2. Chunk-XOR LDS layout: byte = r*1024 + chunk*128 + (off ^ SWZ8(r) ^ (chunk<<4)).
//    Kills the 8-way x-staging write conflicts (all column-chunks aliased at
//    1024-B row stride) and spreads h-handoff writes; af reads stay free.
__global__ __launch_bounds__(512, 3)
void fused_mlp(const float* __restrict__ X,
               const unsigned short* __restrict__ PK1,
               const float* __restrict__ B1,
               const unsigned short* __restrict__ PK2,
               const float* __restrict__ B2,
               float* __restrict__ Out)
{
    __shared__ __align__(16) unsigned char XH[65536];   // [64 rows][1024B]; x then h
    __shared__ __align__(16) float BS[1024];            // [0..511]=b1, [512..1023]=b2

    const int bid = blockIdx.x;
    const int nb = bid & 7;       // XCD-pin heuristic
    const int mt = bid >> 3;      // 0..127

    const int t = threadIdx.x;
    const int lane = t & 63;
    const int wid = t >> 6;       // 0..7 -> col slice wid*64
    const int l15 = lane & 15;
    const int lhi = lane >> 4;

    const int row0 = mt * 64;
    const int wc0  = nb * 512;

    // af bases (chunk-XOR applied per halfstep):
    // addr(m,K) = (ab[m][K&1] + (K>>1)*128) ^ (((K>>1)&7)<<4)
    int ab[4][2];
    #pragma unroll
    for (int m = 0; m < 4; m++) {
        const int r_ = m * 16 + l15;
        #pragma unroll
        for (int p = 0; p < 2; p++)
            ab[m][p] = r_ * 1024 + ((p * 64 + lhi * 16) ^ SWZ8(r_));
    }

    const unsigned short* wp1 = PK1 + (size_t)(nb * 8 + wid) * 32768 + lane * 8;
    const unsigned short* wp2 = PK2 + (size_t)(nb * 8 + wid) * 32768 + lane * 8;

    f32x4 acc[4][4];
    #pragma unroll
    for (int m = 0; m < 4; m++)
        #pragma unroll
        for (int n = 0; n < 4; n++)
            acc[m][n] = (f32x4)(0.f);

    bf16x8 q0[8], q1[8];

// load one kidx-PAIR (8 fragments, 4 KB/wave) and advance
#define LOADQ2(Q, WPTR) { \
    _Pragma("unroll") for (int n = 0; n < 8; n++) \
        Q[n] = *(const bf16x8*)((WPTR) + n * 512); \
    (WPTR) += 4096; \
    __builtin_amdgcn_sched_barrier(0); }

// 16 MFMA on QC[base..base+3] at halfstep K (af via chunk-XOR address)
#define HALF(K, QC, QB) { \
    _Pragma("unroll") for (int m = 0; m < 4; m++) { \
        bf16x8 af = *(const bf16x8*)(XH + ((ab[m][(K) & 1] + ((K) >> 1) * 128) ^ ((((K) >> 1) & 7) << 4))); \
        _Pragma("unroll") for (int n = 0; n < 4; n++) \
            acc[m][n] = __builtin_amdgcn_mfma_f32_16x16x32_bf16(af, QC[(QB) + n], acc[m][n], 0, 0, 0); \
    } }

// pair-step J: issue pair J+1 into QN, compute halfsteps 2J, 2J+1 from QC
#define HSTEP2(J, QC, QN, WPTR) { \
    LOADQ2(QN, WPTR); \
    __builtin_amdgcn_s_setprio(1); \
    HALF(2*(J), QC, 0) \
    HALF(2*(J)+1, QC, 4) \
    __builtin_amdgcn_s_setprio(0); }

#define HSTEP2_NL(J, QC) { \
    __builtin_amdgcn_s_setprio(1); \
    HALF(2*(J), QC, 0) \
    HALF(2*(J)+1, QC, 4) \
    __builtin_amdgcn_s_setprio(0); }

#define BAR() { \
    asm volatile("s_waitcnt lgkmcnt(0)" ::: "memory"); \
    __builtin_amdgcn_s_barrier(); \
    __builtin_amdgcn_sched_barrier(0); }

    // ---- prologue: W1 pair0 (k0,k1) prefetch + bias->LDS + x tile -> XH ----
    LOADQ2(q0, wp1);
    BS[t]       = B1[wc0 + t];
    BS[512 + t] = B2[wc0 + t];
    {
        // stage [64 rows][512 f32] -> bf16, chunk-XOR layout
        const int sr = t >> 3;                        // row 0..63
        const int ch = t & 7;                         // column chunk (128B bf16)
        const float* xr = X + (size_t)(row0 + sr) * DIM + wc0 + ch * 64;
        const int B0 = sr * 1024 + ch * 128 + (SWZ8(sr) ^ (ch << 4));
        #pragma unroll
        for (int i = 0; i < 8; i++) {
            f32x4 a = *(const f32x4*)(xr + i * 8);
            f32x4 b = *(const f32x4*)(xr + i * 8 + 4);
            bf16x8 v;
            ((unsigned long long*)&v)[0] = pack4(a);
            ((unsigned long long*)&v)[1] = pack4(b);
            *(bf16x8*)(XH + (B0 ^ (i * 16))) = v;
        }
    }
    BAR();

    // ================= phase 1: acc = x @ W1^T (barrier-free) =================
    HSTEP2(0, q0, q1, wp1)  HSTEP2(1, q1, q0, wp1)
    HSTEP2(2, q0, q1, wp1)  HSTEP2(3, q1, q0, wp1)
    HSTEP2(4, q0, q1, wp1)  HSTEP2(5, q1, q0, wp1)
    HSTEP2(6, q0, q1, wp1)  HSTEP2(7, q1, q0, wp2)   // last: seed W2 pair0

    BAR();   // all XH(x) ds_reads retired in every wave -> safe to overwrite with h

    // ---- h = relu(acc + b1) -> XH (chunk-XOR layout); bias from LDS ----
    {
        const int hb = wid * 128 + ((l15 * 2) ^ ((wid & 7) << 4));
        #pragma unroll
        for (int n = 0; n < 4; n++) {
            const int c = wid * 64 + n * 16 + l15;
            const float bv = BS[c];
            #pragma unroll
            for (int m = 0; m < 4; m++) {
                #pragma unroll
                for (int rr = 0; rr < 4; rr++) {
                    float v = acc[m][n][rr] + bv;
                    v = v > 0.f ? v : 0.f;
                    const int r = m * 16 + lhi * 4 + rr;
                    *(unsigned short*)(XH + r * 1024 + (hb ^ (n * 32) ^ SWZ8(r))) = f2bf(v);
                }
            }
        }
    }
    BAR();   // h visible to all waves

    #pragma unroll
    for (int m = 0; m < 4; m++)
        #pragma unroll
        for (int n = 0; n < 4; n++)
            acc[m][n] = (f32x4)(0.f);

    // ================= phase 2: acc = h @ W2^T (barrier-free) =================
    HSTEP2(0, q0, q1, wp2)  HSTEP2(1, q1, q0, wp2)
    HSTEP2(2, q0, q1, wp2)  HSTEP2(3, q1, q0, wp2)
    HSTEP2(4, q0, q1, wp2)  HSTEP2(5, q1, q0, wp2)
    HSTEP2(6, q0, q1, wp2)  HSTEP2_NL(7, q1)

    // ---- epilogue: out = relu(acc + b2), f32; bias from LDS ----
    #pragma unroll
    for (int n = 0; n < 4; n++) {
        const int cl = wid * 64 + n * 16 + l15;
        const float bv = BS[512 + cl];
        const int c = wc0 + cl;
        #pragma unroll
        for (int m = 0; m < 4; m++) {
            const int rb = row0 + m * 16 + lhi * 4;
            #pragma unroll
            for (int rr = 0; rr < 4; rr++) {
                float v = acc[m][n][rr] + bv;
                Out[(size_t)(rb + rr) * DIM + c] = v > 0.f ? v : 0.f;
            }
        }
    }

#undef LOADQ2
#undef HALF
#undef HSTEP2
#undef HSTEP2_NL
#undef BAR
}

extern "C" void kernel_launch(void* const* d_in, const int* in_sizes, int n_in,
                              void* d_out, int out_size, void* d_ws, size_t ws_size,
                              hipStream_t stream) {
    const float* x  = (const float*)d_in[0];
    const float* W1 = (const float*)d_in[1];
    const float* b1 = (const float*)d_in[2];
    const float* W2 = (const float*)d_in[3];
    const float* b2 = (const float*)d_in[4];
    float* out = (float*)d_out;

    char* ws = (char*)d_ws;
    unsigned short* PK1 = (unsigned short*)ws;                 // 4 MB
    unsigned short* PK2 = (unsigned short*)(ws + (4u << 20));  // 4 MB

    pack_w<<<1024, 256, 0, stream>>>(W1, PK1);
    pack_w<<<1024, 256, 0, stream>>>(W2, PK2);

    const int GRID = NB * (BATCH / 64);     // 1024
    fused_mlp<<<GRID, 512, 0, stream>>>(x, PK1, b1, PK2, b2, out);
}

// Round 18
// 147.900 us; speedup vs baseline: 1.0246x; 1.0246x over previous
//
#include <hip/hip_runtime.h>
#include <hip/hip_bf16.h>

#define NB 8
#define BIN 512
#define BOUT 512
#define BATCH 8192
#define DIM 4096   // NB*BIN

typedef __attribute__((ext_vector_type(8))) short bf16x8;
typedef __attribute__((ext_vector_type(4))) float f32x4;

#define SWZ8(r) (((r) & 7) << 4)

__device__ __forceinline__ unsigned short f2bf(float f) {
    return __builtin_bit_cast(unsigned short, __float2bfloat16(f));
}

__device__ __forceinline__ unsigned long long pack4(f32x4 f) {
    return (unsigned long long)f2bf(f.x)
         | ((unsigned long long)f2bf(f.y) << 16)
         | ((unsigned long long)f2bf(f.z) << 32)
         | ((unsigned long long)f2bf(f.w) << 48);
}

// ---------------- weight pack (R11 layout) ----------------
// (nb, wid 0..7, kidx 0..15, nf 0..3, lane 0..63) x 8 ushorts, linear.
// Fragment: lane -> row = wid*64 + nf*16 + (lane&15), col = kidx*32 + (lane>>4)*8.
// Per (nb,wid): 32768 ush, advancing 2048 ush per kidx.
__global__ void pack_w(const float* __restrict__ W, unsigned short* __restrict__ pk) {
    int gid = blockIdx.x * 256 + threadIdx.x;        // 262144 total
    int lane = gid & 63;
    int nf   = (gid >> 6) & 3;
    int kidx = (gid >> 8) & 15;
    int wid  = (gid >> 12) & 7;
    int nb   = gid >> 15;
    int row  = wid * 64 + nf * 16 + (lane & 15);     // 0..511 within block
    int col  = kidx * 32 + (lane >> 4) * 8;          // 0..511
    const float* s = W + ((size_t)nb * BOUT + row) * BIN + col;
    f32x4 a = *(const f32x4*)s;
    f32x4 b = *(const f32x4*)(s + 4);
    unsigned long long* d = (unsigned long long*)(pk + (size_t)gid * 8);
    d[0] = pack4(a);
    d[1] = pack4(b);
}

// ---------------- fused 2-layer block-diag MLP ----------------
// EXACT R11 structure (best verified: 97.9 us) + chunk-XOR LDS layout
// (correctness-verified in R17; removes the 8-way x-staging write conflict:
// at 1024-B row stride the chunk index doesn't reach the bank bits, so all
// 8 column-chunks of a row alias one bank span; XOR-ing (ch<<4) into the
// offset spreads them across all 8 spans). af reads remain conflict-free.
// wg: 64 rows x one diagonal block; 512 thr = 8 waves; wave wid owns cols
// wid*64..+64; acc 4x4 f32x4 = 64 AGPR; q 2-deep ping-pong; 4 waves/SIMD,
// 2 wgs/CU. W ledger: wp1 16 advances (prologue + HSTEP 0..14); wp2 16
// (phase-1 HSTEP(15) seeds W2k0, phase-2 HSTEP 0..14).
__global__ __launch_bounds__(512, 4)
void fused_mlp(const float* __restrict__ X,
               const unsigned short* __restrict__ PK1,
               const float* __restrict__ B1,
               const unsigned short* __restrict__ PK2,
               const float* __restrict__ B2,
               float* __restrict__ Out)
{
    __shared__ __align__(16) unsigned char XH[65536];   // [64 rows][1024B]; x then h
    __shared__ __align__(16) float BS[1024];            // [0..511]=b1, [512..1023]=b2

    const int bid = blockIdx.x;
    const int nb = bid & 7;       // XCD-pin heuristic
    const int mt = bid >> 3;      // 0..127

    const int t = threadIdx.x;
    const int lane = t & 63;
    const int wid = t >> 6;       // 0..7 -> col slice wid*64
    const int l15 = lane & 15;
    const int lhi = lane >> 4;

    const int row0 = mt * 64;
    const int wc0  = nb * 512;

    // af bases; chunk-XOR applied at use:
    // addr(m,K) = (ab[m][K&1] + (K>>1)*128) ^ (((K>>1)&7)<<4)
    int ab[4][2];
    #pragma unroll
    for (int m = 0; m < 4; m++) {
        const int r_ = m * 16 + l15;
        #pragma unroll
        for (int p = 0; p < 2; p++)
            ab[m][p] = r_ * 1024 + ((p * 64 + lhi * 16) ^ SWZ8(r_));
    }

    const unsigned short* wp1 = PK1 + (size_t)(nb * 8 + wid) * 32768 + lane * 8;
    const unsigned short* wp2 = PK2 + (size_t)(nb * 8 + wid) * 32768 + lane * 8;

    f32x4 acc[4][4];
    #pragma unroll
    for (int m = 0; m < 4; m++)
        #pragma unroll
        for (int n = 0; n < 4; n++)
            acc[m][n] = (f32x4)(0.f);

    bf16x8 q0[4], q1[4];

#define LOADQ(Q, WPTR) { \
    _Pragma("unroll") for (int n = 0; n < 4; n++) \
        Q[n] = *(const bf16x8*)((WPTR) + n * 512); \
    (WPTR) += 2048; \
    __builtin_amdgcn_sched_barrier(0); }

// halfstep K: issue W loads for K+1 into QN, then af ds_reads + 16 MFMA on QC
#define HSTEP(K, QC, QN, WPTR) { \
    LOADQ(QN, WPTR); \
    __builtin_amdgcn_s_setprio(1); \
    _Pragma("unroll") for (int m = 0; m < 4; m++) { \
        bf16x8 af = *(const bf16x8*)(XH + ((ab[m][(K) & 1] + ((K) >> 1) * 128) ^ ((((K) >> 1) & 7) << 4))); \
        _Pragma("unroll") for (int n = 0; n < 4; n++) \
            acc[m][n] = __builtin_amdgcn_mfma_f32_16x16x32_bf16(af, QC[n], acc[m][n], 0, 0, 0); \
    } \
    __builtin_amdgcn_s_setprio(0); }

#define HSTEP_NL(K, QC) { \
    __builtin_amdgcn_s_setprio(1); \
    _Pragma("unroll") for (int m = 0; m < 4; m++) { \
        bf16x8 af = *(const bf16x8*)(XH + ((ab[m][(K) & 1] + ((K) >> 1) * 128) ^ ((((K) >> 1) & 7) << 4))); \
        _Pragma("unroll") for (int n = 0; n < 4; n++) \
            acc[m][n] = __builtin_amdgcn_mfma_f32_16x16x32_bf16(af, QC[n], acc[m][n], 0, 0, 0); \
    } \
    __builtin_amdgcn_s_setprio(0); }

#define BAR() { \
    asm volatile("s_waitcnt lgkmcnt(0)" ::: "memory"); \
    __builtin_amdgcn_s_barrier(); \
    __builtin_amdgcn_sched_barrier(0); }

    // ---- prologue: W1 kidx0 prefetch + bias->LDS + full x tile -> XH ----
    LOADQ(q0, wp1);
    BS[t]       = B1[wc0 + t];
    BS[512 + t] = B2[wc0 + t];
    {
        // stage [64 rows][512 f32] -> bf16, chunk-XOR layout (conflict-free)
        const int sr = t >> 3;                        // row 0..63
        const int ch = t & 7;                         // 128B column chunk
        const float* xr = X + (size_t)(row0 + sr) * DIM + wc0 + ch * 64;
        const int B0 = sr * 1024 + ch * 128 + (SWZ8(sr) ^ (ch << 4));
        #pragma unroll
        for (int i = 0; i < 8; i++) {
            f32x4 a = *(const f32x4*)(xr + i * 8);
            f32x4 b = *(const f32x4*)(xr + i * 8 + 4);
            bf16x8 v;
            ((unsigned long long*)&v)[0] = pack4(a);
            ((unsigned long long*)&v)[1] = pack4(b);
            *(bf16x8*)(XH + (B0 ^ (i * 16))) = v;
        }
    }
    BAR();

    // ================= phase 1: acc = x @ W1^T (barrier-free) =================
    HSTEP(0,  q0, q1, wp1)  HSTEP(1,  q1, q0, wp1)  HSTEP(2,  q0, q1, wp1)  HSTEP(3,  q1, q0, wp1)
    HSTEP(4,  q0, q1, wp1)  HSTEP(5,  q1, q0, wp1)  HSTEP(6,  q0, q1, wp1)  HSTEP(7,  q1, q0, wp1)
    HSTEP(8,  q0, q1, wp1)  HSTEP(9,  q1, q0, wp1)  HSTEP(10, q0, q1, wp1)  HSTEP(11, q1, q0, wp1)
    HSTEP(12, q0, q1, wp1)  HSTEP(13, q1, q0, wp1)  HSTEP(14, q0, q1, wp1)  HSTEP(15, q1, q0, wp2)

    BAR();   // all XH(x) ds_reads retired in every wave -> safe to overwrite with h

    // ---- h = relu(acc + b1) -> XH (chunk-XOR layout); bias from LDS ----
    {
        const int hb = wid * 128 + ((l15 * 2) ^ ((wid & 7) << 4));
        #pragma unroll
        for (int n = 0; n < 4; n++) {
            const int c = wid * 64 + n * 16 + l15;
            const float bv = BS[c];
            #pragma unroll
            for (int m = 0; m < 4; m++) {
                #pragma unroll
                for (int rr = 0; rr < 4; rr++) {
                    float v = acc[m][n][rr] + bv;
                    v = v > 0.f ? v : 0.f;
                    const int r = m * 16 + lhi * 4 + rr;
                    *(unsigned short*)(XH + r * 1024 + (hb ^ (n * 32) ^ SWZ8(r))) = f2bf(v);
                }
            }
        }
    }
    BAR();   // h visible to all waves

    #pragma unroll
    for (int m = 0; m < 4; m++)
        #pragma unroll
        for (int n = 0; n < 4; n++)
            acc[m][n] = (f32x4)(0.f);

    // ================= phase 2: acc = h @ W2^T (barrier-free) =================
    HSTEP(0,  q0, q1, wp2)  HSTEP(1,  q1, q0, wp2)  HSTEP(2,  q0, q1, wp2)  HSTEP(3,  q1, q0, wp2)
    HSTEP(4,  q0, q1, wp2)  HSTEP(5,  q1, q0, wp2)  HSTEP(6,  q0, q1, wp2)  HSTEP(7,  q1, q0, wp2)
    HSTEP(8,  q0, q1, wp2)  HSTEP(9,  q1, q0, wp2)  HSTEP(10, q0, q1, wp2)  HSTEP(11, q1, q0, wp2)
    HSTEP(12, q0, q1, wp2)  HSTEP(13, q1, q0, wp2)  HSTEP(14, q0, q1, wp2)  HSTEP_NL(15, q1)

    // ---- epilogue: out = relu(acc + b2), f32; bias from LDS ----
    #pragma unroll
    for (int n = 0; n < 4; n++) {
        const int cl = wid * 64 + n * 16 + l15;
        const float bv = BS[512 + cl];
        const int c = wc0 + cl;
        #pragma unroll
        for (int m = 0; m < 4; m++) {
            const int rb = row0 + m * 16 + lhi * 4;
            #pragma unroll
            for (int rr = 0; rr < 4; rr++) {
                float v = acc[m][n][rr] + bv;
                Out[(size_t)(rb + rr) * DIM + c] = v > 0.f ? v : 0.f;
            }
        }
    }

#undef LOADQ
#undef HSTEP
#undef HSTEP_NL
#undef BAR
}

extern "C" void kernel_launch(void* const* d_in, const int* in_sizes, int n_in,
                              void* d_out, int out_size, void* d_ws, size_t ws_size,
                              hipStream_t stream) {
    const float* x  = (const float*)d_in[0];
    const float* W1 = (const float*)d_in[1];
    const float* b1 = (const float*)d_in[2];
    const float* W2 = (const float*)d_in[3];
    const float* b2 = (const float*)d_in[4];
    float* out = (float*)d_out;

    char* ws = (char*)d_ws;
    unsigned short* PK1 = (unsigned short*)ws;                 // 4 MB
    unsigned short* PK2 = (unsigned short*)(ws + (4u << 20));  // 4 MB

    pack_w<<<1024, 256, 0, stream>>>(W1, PK1);
    pack_w<<<1024, 256, 0, stream>>>(W2, PK2);

    const int GRID = NB * (BATCH / 64);     // 1024
    fused_mlp<<<GRID, 512, 0, stream>>>(x, PK1, b1, PK2, b2, out);
}

// Round 19
// 97.961 us; speedup vs baseline: 1.5470x; 1.5098x over previous
//
#include <hip/hip_runtime.h>
#include <hip/hip_bf16.h>

#define NB 8
#define BIN 512
#define BOUT 512
#define BATCH 8192
#define DIM 4096   // NB*BIN

typedef __attribute__((ext_vector_type(8))) short bf16x8;
typedef __attribute__((ext_vector_type(4))) float f32x4;

#define SWZ8(r) (((r) & 7) << 4)

__device__ __forceinline__ unsigned short f2bf(float f) {
    return __builtin_bit_cast(unsigned short, __float2bfloat16(f));
}

__device__ __forceinline__ unsigned long long pack4(f32x4 f) {
    return (unsigned long long)f2bf(f.x)
         | ((unsigned long long)f2bf(f.y) << 16)
         | ((unsigned long long)f2bf(f.z) << 32)
         | ((unsigned long long)f2bf(f.w) << 48);
}

// ---------------- weight pack (R11 layout), both tensors in one launch ----------------
// (nb, wid 0..7, kidx 0..15, nf 0..3, lane 0..63) x 8 ushorts, linear.
// Fragment: lane -> row = wid*64 + nf*16 + (lane&15), col = kidx*32 + (lane>>4)*8.
// Per (nb,wid): 32768 ush, advancing 2048 ush per kidx.
__global__ void pack_w2(const float* __restrict__ W1, unsigned short* __restrict__ pk1,
                        const float* __restrict__ W2, unsigned short* __restrict__ pk2) {
    int g    = blockIdx.x * 256 + threadIdx.x;       // 524288 total
    int gid  = g & 262143;
    int sel  = g >> 18;                              // 0 -> W1, 1 -> W2
    int lane = gid & 63;
    int nf   = (gid >> 6) & 3;
    int kidx = (gid >> 8) & 15;
    int wid  = (gid >> 12) & 7;
    int nb   = gid >> 15;
    int row  = wid * 64 + nf * 16 + (lane & 15);     // 0..511 within block
    int col  = kidx * 32 + (lane >> 4) * 8;          // 0..511
    const float* W = sel ? W2 : W1;
    unsigned short* pk = sel ? pk2 : pk1;
    const float* s = W + ((size_t)nb * BOUT + row) * BIN + col;
    f32x4 a = *(const f32x4*)s;
    f32x4 b = *(const f32x4*)(s + 4);
    unsigned long long* d = (unsigned long long*)(pk + (size_t)gid * 8);
    d[0] = pack4(a);
    d[1] = pack4(b);
}

// ---------------- fused 2-layer block-diag MLP (EXACT R11 — best: 97.9 us) ----------------
// wg: 64 batch rows x one full diagonal block (512 cols). 512 threads = 8 waves;
// wave wid owns cols wid*64..+64. acc = 4x4 f32x4 = 64 AGPR; q 2-deep ping-pong
// (16 VGPR) -> 128 regs/wave total -> 4 waves/SIMD, 2 wgs/CU.
// x tile (64x512 bf16, SWZ8) staged once; both phases are barrier-free halfstep
// streams; sched_barrier(0) after each LOADQ pins the 1-halfstep prefetch lead.
// Bias via LDS. W ledger: wp1 advances 16x (prologue + HSTEP 0..14); wp2 16x
// (phase-1 HSTEP(15) seeds W2k0, phase-2 HSTEP 0..14).
__global__ __launch_bounds__(512, 4)
void fused_mlp(const float* __restrict__ X,
               const unsigned short* __restrict__ PK1,
               const float* __restrict__ B1,
               const unsigned short* __restrict__ PK2,
               const float* __restrict__ B2,
               float* __restrict__ Out)
{
    __shared__ __align__(16) unsigned char XH[65536];   // [64 rows][1024B], SWZ8; x then h
    __shared__ __align__(16) float BS[1024];            // bias: [0..511]=b1, [512..1023]=b2

    const int bid = blockIdx.x;
    const int nb = bid & 7;       // XCD-pin heuristic
    const int mt = bid >> 3;      // 0..127

    const int t = threadIdx.x;
    const int lane = t & 63;
    const int wid = t >> 6;       // 0..7 -> col slice wid*64
    const int l15 = lane & 15;
    const int lhi = lane >> 4;

    const int row0 = mt * 64;
    const int wc0  = nb * 512;

    // A-read bases: r = m*16+l15; addr(m,kk) = ab[m][kk&1] + (kk>>1)*128
    int ab[4][2];
    #pragma unroll
    for (int m = 0; m < 4; m++) {
        const int r_ = m * 16 + l15;
        #pragma unroll
        for (int p = 0; p < 2; p++)
            ab[m][p] = r_ * 1024 + ((p * 64 + lhi * 16) ^ SWZ8(r_));
    }

    const unsigned short* wp1 = PK1 + (size_t)(nb * 8 + wid) * 32768 + lane * 8;
    const unsigned short* wp2 = PK2 + (size_t)(nb * 8 + wid) * 32768 + lane * 8;

    f32x4 acc[4][4];
    #pragma unroll
    for (int m = 0; m < 4; m++)
        #pragma unroll
        for (int n = 0; n < 4; n++)
            acc[m][n] = (f32x4)(0.f);

    bf16x8 q0[4], q1[4];

#define LOADQ(Q, WPTR) { \
    _Pragma("unroll") for (int n = 0; n < 4; n++) \
        Q[n] = *(const bf16x8*)((WPTR) + n * 512); \
    (WPTR) += 2048; \
    __builtin_amdgcn_sched_barrier(0); }

// halfstep K: issue W loads for K+1 into QN, then af ds_reads + 16 MFMA on QC
#define HSTEP(K, QC, QN, WPTR) { \
    LOADQ(QN, WPTR); \
    __builtin_amdgcn_s_setprio(1); \
    _Pragma("unroll") for (int m = 0; m < 4; m++) { \
        bf16x8 af = *(const bf16x8*)(XH + ab[m][(K) & 1] + ((K) >> 1) * 128); \
        _Pragma("unroll") for (int n = 0; n < 4; n++) \
            acc[m][n] = __builtin_amdgcn_mfma_f32_16x16x32_bf16(af, QC[n], acc[m][n], 0, 0, 0); \
    } \
    __builtin_amdgcn_s_setprio(0); }

#define HSTEP_NL(K, QC) { \
    __builtin_amdgcn_s_setprio(1); \
    _Pragma("unroll") for (int m = 0; m < 4; m++) { \
        bf16x8 af = *(const bf16x8*)(XH + ab[m][(K) & 1] + ((K) >> 1) * 128); \
        _Pragma("unroll") for (int n = 0; n < 4; n++) \
            acc[m][n] = __builtin_amdgcn_mfma_f32_16x16x32_bf16(af, QC[n], acc[m][n], 0, 0, 0); \
    } \
    __builtin_amdgcn_s_setprio(0); }

#define BAR() { \
    asm volatile("s_waitcnt lgkmcnt(0)" ::: "memory"); \
    __builtin_amdgcn_s_barrier(); \
    __builtin_amdgcn_sched_barrier(0); }

    // ---- prologue: W1 kidx0 prefetch + bias->LDS + full x tile -> XH ----
    LOADQ(q0, wp1);
    BS[t]       = B1[wc0 + t];
    BS[512 + t] = B2[wc0 + t];
    {
        // 512 threads stage [64 rows][512 f32] -> bf16, SWZ8-swizzled
        const int sr = t >> 3;                        // row 0..63
        const int cb = (t & 7) * 128;                 // byte base within row
        const float* xr = X + (size_t)(row0 + sr) * DIM + wc0 + (t & 7) * 64;
        #pragma unroll
        for (int i = 0; i < 8; i++) {
            f32x4 a = *(const f32x4*)(xr + i * 8);
            f32x4 b = *(const f32x4*)(xr + i * 8 + 4);
            bf16x8 v;
            ((unsigned long long*)&v)[0] = pack4(a);
            ((unsigned long long*)&v)[1] = pack4(b);
            *(bf16x8*)(XH + sr * 1024 + ((cb + i * 16) ^ SWZ8(sr))) = v;
        }
    }
    BAR();

    // ================= phase 1: acc = x @ W1^T (barrier-free) =================
    HSTEP(0,  q0, q1, wp1)  HSTEP(1,  q1, q0, wp1)  HSTEP(2,  q0, q1, wp1)  HSTEP(3,  q1, q0, wp1)
    HSTEP(4,  q0, q1, wp1)  HSTEP(5,  q1, q0, wp1)  HSTEP(6,  q0, q1, wp1)  HSTEP(7,  q1, q0, wp1)
    HSTEP(8,  q0, q1, wp1)  HSTEP(9,  q1, q0, wp1)  HSTEP(10, q0, q1, wp1)  HSTEP(11, q1, q0, wp1)
    HSTEP(12, q0, q1, wp1)  HSTEP(13, q1, q0, wp1)  HSTEP(14, q0, q1, wp1)  HSTEP(15, q1, q0, wp2)

    BAR();   // all XH(x) ds_reads retired in every wave -> safe to overwrite with h

    // ---- h = relu(acc + b1) -> XH (same SWZ8 layout); bias from LDS ----
    #pragma unroll
    for (int n = 0; n < 4; n++) {
        const int c = wid * 64 + n * 16 + l15;
        const float bv = BS[c];
        #pragma unroll
        for (int m = 0; m < 4; m++) {
            #pragma unroll
            for (int rr = 0; rr < 4; rr++) {
                float v = acc[m][n][rr] + bv;
                v = v > 0.f ? v : 0.f;
                const int r = m * 16 + lhi * 4 + rr;
                *(unsigned short*)(XH + r * 1024 + ((c * 2) ^ SWZ8(r))) = f2bf(v);
            }
        }
    }
    BAR();   // h visible to all waves

    #pragma unroll
    for (int m = 0; m < 4; m++)
        #pragma unroll
        for (int n = 0; n < 4; n++)
            acc[m][n] = (f32x4)(0.f);

    // ================= phase 2: acc = h @ W2^T (barrier-free) =================
    HSTEP(0,  q0, q1, wp2)  HSTEP(1,  q1, q0, wp2)  HSTEP(2,  q0, q1, wp2)  HSTEP(3,  q1, q0, wp2)
    HSTEP(4,  q0, q1, wp2)  HSTEP(5,  q1, q0, wp2)  HSTEP(6,  q0, q1, wp2)  HSTEP(7,  q1, q0, wp2)
    HSTEP(8,  q0, q1, wp2)  HSTEP(9,  q1, q0, wp2)  HSTEP(10, q0, q1, wp2)  HSTEP(11, q1, q0, wp2)
    HSTEP(12, q0, q1, wp2)  HSTEP(13, q1, q0, wp2)  HSTEP(14, q0, q1, wp2)  HSTEP_NL(15, q1)

    // ---- epilogue: out = relu(acc + b2), f32; bias from LDS ----
    #pragma unroll
    for (int n = 0; n < 4; n++) {
        const int cl = wid * 64 + n * 16 + l15;
        const float bv = BS[512 + cl];
        const int c = wc0 + cl;
        #pragma unroll
        for (int m = 0; m < 4; m++) {
            const int rb = row0 + m * 16 + lhi * 4;
            #pragma unroll
            for (int rr = 0; rr < 4; rr++) {
                float v = acc[m][n][rr] + bv;
                Out[(size_t)(rb + rr) * DIM + c] = v > 0.f ? v : 0.f;
            }
        }
    }

#undef LOADQ
#undef HSTEP
#undef HSTEP_NL
#undef BAR
}

extern "C" void kernel_launch(void* const* d_in, const int* in_sizes, int n_in,
                              void* d_out, int out_size, void* d_ws, size_t ws_size,
                              hipStream_t stream) {
    const float* x  = (const float*)d_in[0];
    const float* W1 = (const float*)d_in[1];
    const float* b1 = (const float*)d_in[2];
    const float* W2 = (const float*)d_in[3];
    const float* b2 = (const float*)d_in[4];
    float* out = (float*)d_out;

    char* ws = (char*)d_ws;
    unsigned short* PK1 = (unsigned short*)ws;                 // 4 MB
    unsigned short* PK2 = (unsigned short*)(ws + (4u << 20));  // 4 MB

    pack_w2<<<2048, 256, 0, stream>>>(W1, PK1, W2, PK2);

    const int GRID = NB * (BATCH / 64);     // 1024
    fused_mlp<<<GRID, 512, 0, stream>>>(x, PK1, b1, PK2, b2, out);
}